// Round 1
// baseline (482.228 us; speedup 1.0000x reference)
//
#include <hip/hip_runtime.h>

// RNNT joint: out = log_softmax( tanh(enc@W_e + dec@W_d + b1) @ W2 )
// B=4, T=256, U=128, D=512, NCLS=1024.
// ws layout: ep (B*T x D fp32, 2MB) | dp (B*U x D fp32, 1MB) | W2 packed bf16 (1MB)

#define BB 4
#define TT 256
#define UU 128
#define DD 512
#define CC 1024

using f32x16 = __attribute__((ext_vector_type(16))) float;
using bf16x8 = __attribute__((ext_vector_type(8))) __bf16;

static __device__ __forceinline__ unsigned short f2bf(float f) {
    unsigned int u = __float_as_uint(f);
    unsigned int r = (u + 0x7FFFu + ((u >> 16) & 1u)) >> 16;
    return (unsigned short)r;
}

static __device__ __forceinline__ float tanh_fast(float x) {
    x = fminf(15.f, fmaxf(-15.f, x));
    float e = __expf(2.f * x);
    return (e - 1.f) / (e + 1.f);
}

// ---- prep: C[m][n] = sum_k A[m][k]*W[k][n] (+bias), K=N=512 ----
__global__ __launch_bounds__(256) void proj_gemm(
    const float* __restrict__ A, const float* __restrict__ W,
    const float* __restrict__ bias, float* __restrict__ C)
{
    __shared__ float As[32][65];
    __shared__ float Ws[32][64];
    const int m0 = blockIdx.x * 64;
    const int n0 = blockIdx.y * 64;
    const int tid = threadIdx.x;
    const int tx = tid & 15, ty = tid >> 4;
    float acc[4][4] = {};
    for (int k0 = 0; k0 < DD; k0 += 32) {
        __syncthreads();
        #pragma unroll
        for (int i = 0; i < 8; ++i) {
            int idx = tid + i * 256;           // 0..2047 -> 64x32 A tile
            int kk = idx & 31, m = idx >> 5;
            As[kk][m] = A[(size_t)(m0 + m) * DD + k0 + kk];
        }
        #pragma unroll
        for (int i = 0; i < 8; ++i) {
            int idx = tid + i * 256;           // 32x64 W tile
            int n = idx & 63, kk = idx >> 6;
            Ws[kk][n] = W[(size_t)(k0 + kk) * DD + n0 + n];
        }
        __syncthreads();
        #pragma unroll 8
        for (int kk = 0; kk < 32; ++kk) {
            float a[4], wv[4];
            #pragma unroll
            for (int i = 0; i < 4; ++i) a[i] = As[kk][ty * 4 + i];
            #pragma unroll
            for (int j = 0; j < 4; ++j) wv[j] = Ws[kk][tx * 4 + j];
            #pragma unroll
            for (int i = 0; i < 4; ++i)
                #pragma unroll
                for (int j = 0; j < 4; ++j) acc[i][j] += a[i] * wv[j];
        }
    }
    #pragma unroll
    for (int i = 0; i < 4; ++i)
        #pragma unroll
        for (int j = 0; j < 4; ++j) {
            float v = acc[i][j] + (bias ? bias[n0 + tx * 4 + j] : 0.f);
            C[(size_t)(m0 + ty * 4 + i) * DD + n0 + tx * 4 + j] = v;
        }
}

// ---- prep: pack W2 (512x1024 f32) into bf16 fragment-contiguous layout ----
// dest element index for (k,c): ((ktag)*1024 + c)*8 + (k&7),  ktag = k>>3
// (ktag = kk*2+g matches the MFMA fragment k = kk*16 + 8g + j)
__global__ __launch_bounds__(256) void pack_w2(
    const float* __restrict__ W2, unsigned short* __restrict__ w2p)
{
    int i = blockIdx.x * 256 + threadIdx.x;    // 512*1024 total
    int k = i >> 10, c = i & 1023;
    int idx = (((k >> 3) * CC) + c) * 8 + (k & 7);
    w2p[idx] = f2bf(W2[i]);
}

// ---- fused joint kernel ----
// grid = B*T*2 blocks; block handles (b,t, 64 u-rows), 1024 threads = 16 waves.
// wave grid 2(M) x 8(N): wave computes 32 rows x 128 cols via 4x mfma_32x32x16.
__global__ __launch_bounds__(1024) void joint_kernel(
    const float* __restrict__ ep, const float* __restrict__ dp,
    const unsigned short* __restrict__ w2p, float* __restrict__ out)
{
    __shared__ __align__(16) unsigned char ldsA[64 * 1024]; // hidden[64][512] bf16, XOR-swizzled
    __shared__ float maxbuf[2][32][8];
    __shared__ float sumbuf[2][32][8];
    __shared__ float rowmax_s[2][32];
    __shared__ float rowlse[2][32];

    const int bid = blockIdx.x;
    const int bt  = bid >> 1;             // b*T + t
    const int u0  = (bid & 1) * 64;
    const int b   = bt >> 8;              // T=256
    const int tid = threadIdx.x;

    // phase 1: hidden = tanh(ep_row + dp_row) -> LDS bf16 (swizzled 16B chunks)
    {
        const int row = tid >> 4;                 // 0..63 (u - u0)
        const int kb  = (tid & 15) * 8;
        const float* eprow = ep + (size_t)bt * DD;
        const float* dprow = dp + (size_t)(b * UU + u0 + row) * DD;
        const int sw = (row & 7) << 4;
        #pragma unroll
        for (int c = 0; c < 4; ++c) {
            const int k0 = kb + c * 128;
            float4 e0 = *reinterpret_cast<const float4*>(eprow + k0);
            float4 e1 = *reinterpret_cast<const float4*>(eprow + k0 + 4);
            float4 d0 = *reinterpret_cast<const float4*>(dprow + k0);
            float4 d1 = *reinterpret_cast<const float4*>(dprow + k0 + 4);
            float h0 = tanh_fast(e0.x + d0.x), h1 = tanh_fast(e0.y + d0.y);
            float h2 = tanh_fast(e0.z + d0.z), h3 = tanh_fast(e0.w + d0.w);
            float h4 = tanh_fast(e1.x + d1.x), h5 = tanh_fast(e1.y + d1.y);
            float h6 = tanh_fast(e1.z + d1.z), h7 = tanh_fast(e1.w + d1.w);
            uint4 pk;
            pk.x = (unsigned)f2bf(h0) | ((unsigned)f2bf(h1) << 16);
            pk.y = (unsigned)f2bf(h2) | ((unsigned)f2bf(h3) << 16);
            pk.z = (unsigned)f2bf(h4) | ((unsigned)f2bf(h5) << 16);
            pk.w = (unsigned)f2bf(h6) | ((unsigned)f2bf(h7) << 16);
            *reinterpret_cast<uint4*>(ldsA + row * 1024 + ((k0 * 2) ^ sw)) = pk;
        }
    }
    __syncthreads();

    const int lane = tid & 63;
    const int w    = tid >> 6;            // 0..15
    const int g    = lane >> 5;           // k-half
    const int l31  = lane & 31;
    const int mr   = w >> 3;              // 0/1 : which 32 u-rows
    const int nc   = w & 7;               // 0..7 : which 128 cols

    const int arow = mr * 32 + l31;
    const unsigned char* abase = ldsA + arow * 1024;
    const int asw = (arow & 7) << 4;
    const unsigned short* wbase = w2p + (nc * 128 + l31) * 8;

    f32x16 acc0 = {}, acc1 = {}, acc2 = {}, acc3 = {};

    #pragma unroll 2
    for (int kk = 0; kk < 32; ++kk) {
        const int ktag = kk * 2 + g;
        bf16x8 af = *reinterpret_cast<const bf16x8*>(abase + ((ktag << 4) ^ asw));
        const unsigned short* wk = wbase + (size_t)ktag * (CC * 8);
        bf16x8 b0 = *reinterpret_cast<const bf16x8*>(wk);
        bf16x8 b1 = *reinterpret_cast<const bf16x8*>(wk + 256);
        bf16x8 b2 = *reinterpret_cast<const bf16x8*>(wk + 512);
        bf16x8 b3 = *reinterpret_cast<const bf16x8*>(wk + 768);
        acc0 = __builtin_amdgcn_mfma_f32_32x32x16_bf16(af, b0, acc0, 0, 0, 0);
        acc1 = __builtin_amdgcn_mfma_f32_32x32x16_bf16(af, b1, acc1, 0, 0, 0);
        acc2 = __builtin_amdgcn_mfma_f32_32x32x16_bf16(af, b2, acc2, 0, 0, 0);
        acc3 = __builtin_amdgcn_mfma_f32_32x32x16_bf16(af, b3, acc3, 0, 0, 0);
    }

    // row max: per-lane over 4 N-tiles, butterfly over 32-lane col group,
    // then cross-wave combine in LDS. C/D layout: col=l31, row=(r&3)+8*(r>>2)+4*g.
    float pr[16];
    #pragma unroll
    for (int r = 0; r < 16; ++r)
        pr[r] = fmaxf(fmaxf(acc0[r], acc1[r]), fmaxf(acc2[r], acc3[r]));
    #pragma unroll
    for (int off = 16; off >= 1; off >>= 1) {
        #pragma unroll
        for (int r = 0; r < 16; ++r)
            pr[r] = fmaxf(pr[r], __shfl_xor(pr[r], off, 64));
    }
    if (l31 == 0) {
        #pragma unroll
        for (int r = 0; r < 16; ++r) {
            int r32 = (r & 3) + 8 * (r >> 2) + 4 * g;
            maxbuf[mr][r32][nc] = pr[r];
        }
    }
    __syncthreads();
    if (tid < 64) {
        int m_ = tid >> 5, rr = tid & 31;
        float m = maxbuf[m_][rr][0];
        #pragma unroll
        for (int j = 1; j < 8; ++j) m = fmaxf(m, maxbuf[m_][rr][j]);
        rowmax_s[m_][rr] = m;
    }
    __syncthreads();

    float ps[16];
    #pragma unroll
    for (int r = 0; r < 16; ++r) {
        int r32 = (r & 3) + 8 * (r >> 2) + 4 * g;
        float rm = rowmax_s[mr][r32];
        ps[r] = __expf(acc0[r] - rm) + __expf(acc1[r] - rm)
              + __expf(acc2[r] - rm) + __expf(acc3[r] - rm);
    }
    #pragma unroll
    for (int off = 16; off >= 1; off >>= 1) {
        #pragma unroll
        for (int r = 0; r < 16; ++r)
            ps[r] += __shfl_xor(ps[r], off, 64);
    }
    if (l31 == 0) {
        #pragma unroll
        for (int r = 0; r < 16; ++r) {
            int r32 = (r & 3) + 8 * (r >> 2) + 4 * g;
            sumbuf[mr][r32][nc] = ps[r];
        }
    }
    __syncthreads();
    if (tid < 64) {
        int m_ = tid >> 5, rr = tid & 31;
        float s = 0.f;
        #pragma unroll
        for (int j = 0; j < 8; ++j) s += sumbuf[m_][rr][j];
        rowlse[m_][rr] = rowmax_s[m_][rr] + __logf(s);
    }
    __syncthreads();

    float* outp = out + ((size_t)bt * UU + u0 + mr * 32) * CC + nc * 128 + l31;
    #pragma unroll
    for (int r = 0; r < 16; ++r) {
        int r32 = (r & 3) + 8 * (r >> 2) + 4 * g;
        float l = rowlse[mr][r32];
        __builtin_nontemporal_store(acc0[r] - l, outp + (size_t)r32 * CC + 0);
        __builtin_nontemporal_store(acc1[r] - l, outp + (size_t)r32 * CC + 32);
        __builtin_nontemporal_store(acc2[r] - l, outp + (size_t)r32 * CC + 64);
        __builtin_nontemporal_store(acc3[r] - l, outp + (size_t)r32 * CC + 96);
    }
}

extern "C" void kernel_launch(void* const* d_in, const int* in_sizes, int n_in,
                              void* d_out, int out_size, void* d_ws, size_t ws_size,
                              hipStream_t stream) {
    const float* enc = (const float*)d_in[0];   // (B,T,D)
    const float* dec = (const float*)d_in[1];   // (B,U,D)
    const float* W_e = (const float*)d_in[2];   // (D,D)
    const float* W_d = (const float*)d_in[3];   // (D,D)
    const float* b1  = (const float*)d_in[4];   // (D,)
    const float* W2  = (const float*)d_in[5];   // (D,NCLS)
    float* out = (float*)d_out;

    char* ws = (char*)d_ws;                     // needs 4 MB
    float* ep = (float*)(ws);                   // (B*T, D) fp32
    float* dp = (float*)(ws + (2u << 20));      // (B*U, D) fp32
    unsigned short* w2p = (unsigned short*)(ws + (3u << 20)); // packed bf16

    hipLaunchKernelGGL(pack_w2, dim3((DD * CC) / 256), dim3(256), 0, stream, W2, w2p);
    hipLaunchKernelGGL(proj_gemm, dim3((BB * TT) / 64, DD / 64), dim3(256), 0, stream,
                       enc, W_e, b1, ep);
    hipLaunchKernelGGL(proj_gemm, dim3((BB * UU) / 64, DD / 64), dim3(256), 0, stream,
                       dec, W_d, (const float*)nullptr, dp);
    hipLaunchKernelGGL(joint_kernel, dim3(BB * TT * 2), dim3(1024), 0, stream,
                       ep, dp, w2p, out);
}

// Round 2
// 353.879 us; speedup vs baseline: 1.3627x; 1.3627x over previous
//
#include <hip/hip_runtime.h>

// RNNT joint: out = log_softmax( tanh(enc@W_e + dec@W_d + b1) @ W2 )
// B=4, T=256, U=128, D=512, NCLS=1024.
// ws layout: ep (B*T x D fp32, 2MB) | dp (B*U x D fp32, 1MB) | W2 packed bf16 (1MB)

#define BB 4
#define TT 256
#define UU 128
#define DD 512
#define CC 1024

using f32x16 = __attribute__((ext_vector_type(16))) float;
using bf16x8 = __attribute__((ext_vector_type(8))) __bf16;

static __device__ __forceinline__ unsigned short f2bf(float f) {
    unsigned int u = __float_as_uint(f);
    unsigned int r = (u + 0x7FFFu + ((u >> 16) & 1u)) >> 16;
    return (unsigned short)r;
}

static __device__ __forceinline__ float tanh_fast(float x) {
    x = fminf(15.f, fmaxf(-15.f, x));
    float e = __expf(2.f * x);
    return (e - 1.f) / (e + 1.f);
}

// ---- prep: fused enc/dec projection. C[m][n] = A[m][:] @ W[:][n] (+bias) ----
// rows 0..1023 -> enc@W_e + b1 -> ep ; rows 1024..1535 -> dec@W_d -> dp
__global__ __launch_bounds__(256) void proj_fused(
    const float* __restrict__ enc, const float* __restrict__ dec,
    const float* __restrict__ W_e, const float* __restrict__ W_d,
    const float* __restrict__ b1,
    float* __restrict__ ep, float* __restrict__ dp)
{
    __shared__ float As[32][34];   // [k][row], stride 34 keeps b64 reads aligned
    __shared__ float Ws[32][68];   // [k][col], stride 68 keeps b128 reads aligned
    const int mb = blockIdx.x * 32;
    const int n0 = blockIdx.y * 64;
    const bool is_enc = (mb < BB * TT);
    const float* A = is_enc ? enc + (size_t)mb * DD
                            : dec + (size_t)(mb - BB * TT) * DD;
    const float* W = is_enc ? W_e : W_d;
    float* C = is_enc ? ep + (size_t)mb * DD
                      : dp + (size_t)(mb - BB * TT) * DD;
    const int tid = threadIdx.x;
    const int tx = tid & 15, ty = tid >> 4;
    float acc[2][4] = {};
    for (int k0 = 0; k0 < DD; k0 += 32) {
        __syncthreads();
        {
            const int row = tid >> 3, kk = (tid & 7) * 4;   // A: 32x32
            float4 v = *reinterpret_cast<const float4*>(A + (size_t)row * DD + k0 + kk);
            As[kk][row] = v.x; As[kk + 1][row] = v.y;
            As[kk + 2][row] = v.z; As[kk + 3][row] = v.w;
            const int wk = tid >> 3, wc = (tid & 7) * 8;    // W: 32x64
            float4 w0 = *reinterpret_cast<const float4*>(W + (size_t)(k0 + wk) * DD + n0 + wc);
            float4 w1 = *reinterpret_cast<const float4*>(W + (size_t)(k0 + wk) * DD + n0 + wc + 4);
            *reinterpret_cast<float4*>(&Ws[wk][wc]) = w0;
            *reinterpret_cast<float4*>(&Ws[wk][wc + 4]) = w1;
        }
        __syncthreads();
        #pragma unroll 4
        for (int kk = 0; kk < 32; ++kk) {
            float a0 = As[kk][ty * 2], a1 = As[kk][ty * 2 + 1];
            float w0 = Ws[kk][tx * 4], w1 = Ws[kk][tx * 4 + 1];
            float w2 = Ws[kk][tx * 4 + 2], w3 = Ws[kk][tx * 4 + 3];
            acc[0][0] += a0 * w0; acc[0][1] += a0 * w1;
            acc[0][2] += a0 * w2; acc[0][3] += a0 * w3;
            acc[1][0] += a1 * w0; acc[1][1] += a1 * w1;
            acc[1][2] += a1 * w2; acc[1][3] += a1 * w3;
        }
    }
    float bb[4] = {0.f, 0.f, 0.f, 0.f};
    if (is_enc) {
        #pragma unroll
        for (int j = 0; j < 4; ++j) bb[j] = b1[n0 + tx * 4 + j];
    }
    #pragma unroll
    for (int i = 0; i < 2; ++i) {
        float4 v;
        v.x = acc[i][0] + bb[0]; v.y = acc[i][1] + bb[1];
        v.z = acc[i][2] + bb[2]; v.w = acc[i][3] + bb[3];
        *reinterpret_cast<float4*>(C + (size_t)(ty * 2 + i) * DD + n0 + tx * 4) = v;
    }
}

// ---- prep: pack W2 (512x1024 f32) into bf16 fragment-contiguous layout ----
// dest element index for (k,c): ((k>>3)*1024 + c)*8 + (k&7)
__global__ __launch_bounds__(256) void pack_w2(
    const float* __restrict__ W2, unsigned short* __restrict__ w2p)
{
    int i = blockIdx.x * 256 + threadIdx.x;    // 512*1024 total
    int k = i >> 10, c = i & 1023;
    int idx = (((k >> 3) * CC) + c) * 8 + (k & 7);
    w2p[idx] = f2bf(W2[i]);
}

// ---- fused joint kernel ----
// grid = B*T*2 blocks; block handles (b,t, 64 u-rows), 1024 threads = 16 waves.
// wave-tile = 64 rows x 64 cols (2x2 mfma_32x32x16 tiles): each W2 fragment
// feeds 64 output rows -> W2 L2 traffic 2.1 GB (was 4.3 GB at 32x128).
// hidden LDS layout is fragment-major [ktag][row^(ktag&7)][16B] -> conflict-free
// b128 reads AND conflict-free phase-1 writes.
__global__ __launch_bounds__(1024) void joint_kernel(
    const float* __restrict__ ep, const float* __restrict__ dp,
    const unsigned short* __restrict__ w2p, float* __restrict__ out)
{
    __shared__ __align__(16) unsigned char ldsA[64 * 1024]; // [ktag 0..63][1024B]
    __shared__ float maxbuf[64][17];
    __shared__ float sumbuf[64][17];
    __shared__ float rowmax_s[64];
    __shared__ float rowlse[64];

    const int bid = blockIdx.x;
    const int bt  = bid >> 1;             // b*T + t
    const int u0  = (bid & 1) * 64;
    const int b   = bt >> 8;              // T=256
    const int tid = threadIdx.x;

    // phase 1: hidden = tanh(ep_row + dp_row) -> LDS bf16, fragment-major
    {
        const int row = tid >> 4;                 // 0..63 (u - u0)
        const int kq  = tid & 15;
        const float* eprow = ep + (size_t)bt * DD;
        const float* dprow = dp + (size_t)(b * UU + u0 + row) * DD;
        #pragma unroll
        for (int c = 0; c < 4; ++c) {
            const int ktag = kq + c * 16;         // 8 consecutive k = one fragment
            const int k0 = ktag * 8;
            float4 e0 = *reinterpret_cast<const float4*>(eprow + k0);
            float4 e1 = *reinterpret_cast<const float4*>(eprow + k0 + 4);
            float4 d0 = *reinterpret_cast<const float4*>(dprow + k0);
            float4 d1 = *reinterpret_cast<const float4*>(dprow + k0 + 4);
            float h0 = tanh_fast(e0.x + d0.x), h1 = tanh_fast(e0.y + d0.y);
            float h2 = tanh_fast(e0.z + d0.z), h3 = tanh_fast(e0.w + d0.w);
            float h4 = tanh_fast(e1.x + d1.x), h5 = tanh_fast(e1.y + d1.y);
            float h6 = tanh_fast(e1.z + d1.z), h7 = tanh_fast(e1.w + d1.w);
            uint4 pk;
            pk.x = (unsigned)f2bf(h0) | ((unsigned)f2bf(h1) << 16);
            pk.y = (unsigned)f2bf(h2) | ((unsigned)f2bf(h3) << 16);
            pk.z = (unsigned)f2bf(h4) | ((unsigned)f2bf(h5) << 16);
            pk.w = (unsigned)f2bf(h6) | ((unsigned)f2bf(h7) << 16);
            *reinterpret_cast<uint4*>(ldsA + ktag * 1024 + ((row ^ (ktag & 7)) << 4)) = pk;
        }
    }
    __syncthreads();

    const int lane = tid & 63;
    const int w    = tid >> 6;            // 0..15 : 64-col slice
    const int g    = lane >> 5;           // k-half
    const int l31  = lane & 31;
    const int col0 = w * 64;

    const unsigned short* wb0 = w2p + (size_t)(col0 + l31) * 8;
    const unsigned short* wb1 = w2p + (size_t)(col0 + 32 + l31) * 8;

    f32x16 acc00 = {}, acc01 = {}, acc10 = {}, acc11 = {};

    bf16x8 bf0 = *reinterpret_cast<const bf16x8*>(wb0 + (size_t)g * (CC * 8));
    bf16x8 bf1 = *reinterpret_cast<const bf16x8*>(wb1 + (size_t)g * (CC * 8));

    #pragma unroll 2
    for (int kk = 0; kk < 32; ++kk) {
        const int ktag = kk * 2 + g;
        const unsigned char* ab = ldsA + ktag * 1024 + ((l31 ^ (ktag & 7)) << 4);
        bf16x8 a0 = *reinterpret_cast<const bf16x8*>(ab);
        bf16x8 a1 = *reinterpret_cast<const bf16x8*>(ab + 512);  // rows 32..63
        const int ktn = ((kk + 1) & 31) * 2 + g;                 // prefetch next B
        bf16x8 nb0 = *reinterpret_cast<const bf16x8*>(wb0 + (size_t)ktn * (CC * 8));
        bf16x8 nb1 = *reinterpret_cast<const bf16x8*>(wb1 + (size_t)ktn * (CC * 8));
        acc00 = __builtin_amdgcn_mfma_f32_32x32x16_bf16(a0, bf0, acc00, 0, 0, 0);
        acc10 = __builtin_amdgcn_mfma_f32_32x32x16_bf16(a1, bf0, acc10, 0, 0, 0);
        acc01 = __builtin_amdgcn_mfma_f32_32x32x16_bf16(a0, bf1, acc01, 0, 0, 0);
        acc11 = __builtin_amdgcn_mfma_f32_32x32x16_bf16(a1, bf1, acc11, 0, 0, 0);
        bf0 = nb0; bf1 = nb1;
    }

    // ---- log-softmax epilogue. C/D layout: col=l31, row=(r&3)+8*(r>>2)+4*g ----
    #pragma unroll
    for (int i = 0; i < 2; ++i) {
        float pr[16];
        #pragma unroll
        for (int r = 0; r < 16; ++r)
            pr[r] = (i == 0) ? fmaxf(acc00[r], acc01[r]) : fmaxf(acc10[r], acc11[r]);
        #pragma unroll
        for (int off = 16; off >= 1; off >>= 1)
            #pragma unroll
            for (int r = 0; r < 16; ++r)
                pr[r] = fmaxf(pr[r], __shfl_xor(pr[r], off, 64));
        if (l31 == 0)
            #pragma unroll
            for (int r = 0; r < 16; ++r)
                maxbuf[i * 32 + (r & 3) + 8 * (r >> 2) + 4 * g][w] = pr[r];
    }
    __syncthreads();
    if (tid < 64) {
        float m = maxbuf[tid][0];
        #pragma unroll
        for (int j = 1; j < 16; ++j) m = fmaxf(m, maxbuf[tid][j]);
        rowmax_s[tid] = m;
    }
    __syncthreads();
    #pragma unroll
    for (int i = 0; i < 2; ++i) {
        float ps[16];
        #pragma unroll
        for (int r = 0; r < 16; ++r) {
            const int r32 = i * 32 + (r & 3) + 8 * (r >> 2) + 4 * g;
            const float rm = rowmax_s[r32];
            ps[r] = (i == 0) ? __expf(acc00[r] - rm) + __expf(acc01[r] - rm)
                             : __expf(acc10[r] - rm) + __expf(acc11[r] - rm);
        }
        #pragma unroll
        for (int off = 16; off >= 1; off >>= 1)
            #pragma unroll
            for (int r = 0; r < 16; ++r)
                ps[r] += __shfl_xor(ps[r], off, 64);
        if (l31 == 0)
            #pragma unroll
            for (int r = 0; r < 16; ++r)
                sumbuf[i * 32 + (r & 3) + 8 * (r >> 2) + 4 * g][w] = ps[r];
    }
    __syncthreads();
    if (tid < 64) {
        float s = 0.f;
        #pragma unroll
        for (int j = 0; j < 16; ++j) s += sumbuf[tid][j];
        rowlse[tid] = rowmax_s[tid] + __logf(s);
    }
    __syncthreads();

    float* outp = out + ((size_t)(bt * UU + u0)) * CC + col0 + l31;
    #pragma unroll
    for (int r = 0; r < 16; ++r) {
        const int r32 = (r & 3) + 8 * (r >> 2) + 4 * g;
        const float l0 = rowlse[r32];
        const float l1 = rowlse[32 + r32];
        __builtin_nontemporal_store(acc00[r] - l0, outp + (size_t)r32 * CC);
        __builtin_nontemporal_store(acc01[r] - l0, outp + (size_t)r32 * CC + 32);
        __builtin_nontemporal_store(acc10[r] - l1, outp + (size_t)(32 + r32) * CC);
        __builtin_nontemporal_store(acc11[r] - l1, outp + (size_t)(32 + r32) * CC + 32);
    }
}

extern "C" void kernel_launch(void* const* d_in, const int* in_sizes, int n_in,
                              void* d_out, int out_size, void* d_ws, size_t ws_size,
                              hipStream_t stream) {
    const float* enc = (const float*)d_in[0];   // (B,T,D)
    const float* dec = (const float*)d_in[1];   // (B,U,D)
    const float* W_e = (const float*)d_in[2];   // (D,D)
    const float* W_d = (const float*)d_in[3];   // (D,D)
    const float* b1  = (const float*)d_in[4];   // (D,)
    const float* W2  = (const float*)d_in[5];   // (D,NCLS)
    float* out = (float*)d_out;

    char* ws = (char*)d_ws;                     // needs 4 MB
    float* ep = (float*)(ws);                   // (B*T, D) fp32
    float* dp = (float*)(ws + (2u << 20));      // (B*U, D) fp32
    unsigned short* w2p = (unsigned short*)(ws + (3u << 20)); // packed bf16

    hipLaunchKernelGGL(pack_w2, dim3((DD * CC) / 256), dim3(256), 0, stream, W2, w2p);
    hipLaunchKernelGGL(proj_fused, dim3((BB * TT + BB * UU) / 32, DD / 64), dim3(256), 0,
                       stream, enc, dec, W_e, W_d, b1, ep, dp);
    hipLaunchKernelGGL(joint_kernel, dim3(BB * TT * 2), dim3(1024), 0, stream,
                       ep, dp, w2p, out);
}